// Round 10
// baseline (633.401 us; speedup 1.0000x reference)
//
#include <hip/hip_runtime.h>
#include <math.h>

#define B_    16
#define N_    577
#define C_    768
#define H_    12
#define HD_   64
#define M_    (B_ * N_)          // 9232
#define QKV_N 2304
#define QK32_N 1536              // fp32 qkv stride (Q,K only — cls path)
#define NIMG  576
#define BIAS_DIM 640

typedef _Float16 half8  __attribute__((ext_vector_type(8)));
typedef _Float16 half4v __attribute__((ext_vector_type(4)));
typedef float    floatx4 __attribute__((ext_vector_type(4)));

// ---- workspace layout (f32 units), ~161.6 MB ----
// Region A [0, 14,180,352): fp32 qkv Q|K (stride 1536) during GEMM+cls;
//   after select it is DEAD and re-used as: attnh@0, attnl@3,545,088, xout@7,090,176.
#define OFF_QKV32    0u
#define OFF_ATTNH    0u            // f16, 7,090,176 elems
#define OFF_ATTNL    3545088u     // f16, 7,090,176 elems
#define OFF_XOUT     7090176u     // f32, 7,090,176
#define OFF_QKVH     14180352u    // f16, 21,270,528 elems
#define OFF_QKVL     24815616u    // f16, 21,270,528 elems
#define OFF_CLS      35450880u    // 9,216
#define OFF_CLSPART  35460096u    // 110,592
#define OFF_META     35570688u    // 12,288 ints (meta8 + keep576 + img9216)
#define OFF_WQKVH    35582976u    // f16 1,769,472
#define OFF_WQKVL    36467712u
#define OFF_WPROJH   37352448u    // f16 589,824
#define OFF_WPROJL   37647360u
#define OFF_BIASPAD  37942272u    // f16 12*640*640 = 4,915,200
// end = 40,399,872 f32 = 161.6 MB

// ======================= fp32 -> hi/lo f16 split (weights) =======================
__global__ __launch_bounds__(256) void split_kernel(const float* __restrict__ in,
                                                    _Float16* __restrict__ hi,
                                                    _Float16* __restrict__ lo, int n) {
    int i = (blockIdx.x * 256 + threadIdx.x) * 4;
    if (i >= n) return;
    float4 v = *(const float4*)(in + i);
    half4v h, l;
    float vv[4] = {v.x, v.y, v.z, v.w};
#pragma unroll
    for (int j = 0; j < 4; ++j) {
        _Float16 hj = (_Float16)vv[j];
        h[j] = hj;
        l[j] = (_Float16)(vv[j] - (float)hj);
    }
    *(half4v*)(hi + i) = h;
    *(half4v*)(lo + i) = l;
}

// ========== bias_pad[h][i][j] (640x640, -30000 fill) ==========
__global__ __launch_bounds__(256) void bias_expand(const float* __restrict__ bias_table,
                                                   const int* __restrict__ rel_index,
                                                   _Float16* __restrict__ bias_pad) {
    int i = blockIdx.x, h = blockIdx.y;
    _Float16* dst = bias_pad + ((size_t)h * BIAS_DIM + i) * BIAS_DIM;
    const _Float16 NEG = (_Float16)(-30000.f);
    if (i < N_) {
        const int* ri = rel_index + (size_t)i * N_;
        for (int j = threadIdx.x; j < BIAS_DIM; j += 256)
            dst[j] = (j < N_) ? (_Float16)bias_table[ri[j] * H_ + h] : NEG;
    } else {
        for (int j = threadIdx.x; j < BIAS_DIM; j += 256) dst[j] = NEG;
    }
}

// ======================= qkv GEMM: A fp32 (split on stage), B pre-split =======================
// Writes fp32 Q|K (stride 1536, cls path) + full hi/lo f16 planes (Q pre-scaled by 0.125).
__global__ __launch_bounds__(256) void hgemm_qkv(const float* __restrict__ A,
                                                 const _Float16* __restrict__ Bh,
                                                 const _Float16* __restrict__ Bl,
                                                 float* __restrict__ qkv32,
                                                 _Float16* __restrict__ qh_,
                                                 _Float16* __restrict__ ql_) {
    const int K = 768;
    __shared__ __attribute__((aligned(16))) _Float16 Ah_s[128][40];
    __shared__ __attribute__((aligned(16))) _Float16 Al_s[128][40];
    __shared__ __attribute__((aligned(16))) _Float16 Bh_s[128][40];
    __shared__ __attribute__((aligned(16))) _Float16 Bl_s[128][40];

    int tid = threadIdx.x;
    int wave = tid >> 6, lane = tid & 63;
    int g = lane >> 4, c = lane & 15;
    int wr = wave >> 1, wc = wave & 1;
    int m0 = blockIdx.y * 128, n0 = blockIdx.x * 128;

    floatx4 acc[4][4];
#pragma unroll
    for (int mi = 0; mi < 4; ++mi)
#pragma unroll
        for (int ni = 0; ni < 4; ++ni) { acc[mi][ni][0] = 0.f; acc[mi][ni][1] = 0.f; acc[mi][ni][2] = 0.f; acc[mi][ni][3] = 0.f; }

    int lr = tid >> 2;
    int lc = (tid & 3) << 3;

    for (int k0 = 0; k0 < K; k0 += 32) {
        __syncthreads();
#pragma unroll
        for (int hh = 0; hh < 2; ++hh) {
            int r2 = lr + hh * 64;
            int arow = m0 + r2; if (arow >= M_) arow = M_ - 1;    // clamp: A is the input tensor
            const float* ap = A + (size_t)arow * K + k0 + lc;
            floatx4 a0 = *(const floatx4*)ap;
            floatx4 a1 = *(const floatx4*)(ap + 4);
            half8 ah, al;
#pragma unroll
            for (int i = 0; i < 4; ++i) {
                _Float16 h0 = (_Float16)a0[i];
                ah[i] = h0; al[i] = (_Float16)(a0[i] - (float)h0);
                _Float16 h1 = (_Float16)a1[i];
                ah[i + 4] = h1; al[i + 4] = (_Float16)(a1[i] - (float)h1);
            }
            *(half8*)&Ah_s[r2][lc] = ah;
            *(half8*)&Al_s[r2][lc] = al;
            size_t gb = (size_t)(n0 + r2) * K + k0 + lc;
            *(half8*)&Bh_s[r2][lc] = *(const half8*)(Bh + gb);
            *(half8*)&Bl_s[r2][lc] = *(const half8*)(Bl + gb);
        }
        __syncthreads();

        half8 af_h[4], af_l[4];
#pragma unroll
        for (int mi = 0; mi < 4; ++mi) {
            af_h[mi] = *(const half8*)&Ah_s[wr * 64 + mi * 16 + c][g * 8];
            af_l[mi] = *(const half8*)&Al_s[wr * 64 + mi * 16 + c][g * 8];
        }
#pragma unroll
        for (int ni = 0; ni < 4; ++ni) {
            half8 bf_h = *(const half8*)&Bh_s[wc * 64 + ni * 16 + c][g * 8];
            half8 bf_l = *(const half8*)&Bl_s[wc * 64 + ni * 16 + c][g * 8];
#pragma unroll
            for (int mi = 0; mi < 4; ++mi) {
                acc[mi][ni] = __builtin_amdgcn_mfma_f32_16x16x32_f16(af_h[mi], bf_h, acc[mi][ni], 0, 0, 0);
                acc[mi][ni] = __builtin_amdgcn_mfma_f32_16x16x32_f16(af_h[mi], bf_l, acc[mi][ni], 0, 0, 0);
                acc[mi][ni] = __builtin_amdgcn_mfma_f32_16x16x32_f16(af_l[mi], bf_h, acc[mi][ni], 0, 0, 0);
            }
        }
    }

#pragma unroll
    for (int ni = 0; ni < 4; ++ni) {
        int col = n0 + wc * 64 + ni * 16 + c;
#pragma unroll
        for (int mi = 0; mi < 4; ++mi) {
#pragma unroll
            for (int r = 0; r < 4; ++r) {
                int row = m0 + wr * 64 + mi * 16 + 4 * g + r;
                if (row < M_) {
                    float v = acc[mi][ni][r];
                    if (col < QK32_N) qkv32[(size_t)row * QK32_N + col] = v;
                    float sv = (col < 768) ? v * 0.125f : v;   // pre-scale Q (exact pow2)
                    _Float16 hi = (_Float16)sv;
                    size_t idx = (size_t)row * QKV_N + col;
                    qh_[idx] = hi;
                    ql_[idx] = (_Float16)(sv - (float)hi);
                }
            }
        }
    }
}

// ======================= pre-split MFMA GEMM (proj): C = A @ B^T + bias =======================
__global__ __launch_bounds__(256) void hgemm_nt_split(const _Float16* __restrict__ Ah,
                                                      const _Float16* __restrict__ Al,
                                                      const _Float16* __restrict__ Bh,
                                                      const _Float16* __restrict__ Bl,
                                                      const float* __restrict__ bias,
                                                      float* __restrict__ Cout,
                                                      int M, int Nout) {
    const int K = 768;
    __shared__ __attribute__((aligned(16))) _Float16 Ah_s[128][40];
    __shared__ __attribute__((aligned(16))) _Float16 Al_s[128][40];
    __shared__ __attribute__((aligned(16))) _Float16 Bh_s[128][40];
    __shared__ __attribute__((aligned(16))) _Float16 Bl_s[128][40];

    int tid = threadIdx.x;
    int wave = tid >> 6, lane = tid & 63;
    int g = lane >> 4, c = lane & 15;
    int wr = wave >> 1, wc = wave & 1;
    int m0 = blockIdx.y * 128, n0 = blockIdx.x * 128;

    floatx4 acc[4][4];
#pragma unroll
    for (int mi = 0; mi < 4; ++mi)
#pragma unroll
        for (int ni = 0; ni < 4; ++ni) { acc[mi][ni][0] = 0.f; acc[mi][ni][1] = 0.f; acc[mi][ni][2] = 0.f; acc[mi][ni][3] = 0.f; }

    int lr = tid >> 2;
    int lc = (tid & 3) << 3;

    for (int k0 = 0; k0 < K; k0 += 32) {
        __syncthreads();
#pragma unroll
        for (int hh = 0; hh < 2; ++hh) {
            int r2 = lr + hh * 64;
            size_t ga = (size_t)(m0 + r2) * K + k0 + lc;   // overrun reads stay inside ws
            size_t gb = (size_t)(n0 + r2) * K + k0 + lc;
            *(half8*)&Ah_s[r2][lc] = *(const half8*)(Ah + ga);
            *(half8*)&Al_s[r2][lc] = *(const half8*)(Al + ga);
            *(half8*)&Bh_s[r2][lc] = *(const half8*)(Bh + gb);
            *(half8*)&Bl_s[r2][lc] = *(const half8*)(Bl + gb);
        }
        __syncthreads();

        half8 af_h[4], af_l[4];
#pragma unroll
        for (int mi = 0; mi < 4; ++mi) {
            af_h[mi] = *(const half8*)&Ah_s[wr * 64 + mi * 16 + c][g * 8];
            af_l[mi] = *(const half8*)&Al_s[wr * 64 + mi * 16 + c][g * 8];
        }
#pragma unroll
        for (int ni = 0; ni < 4; ++ni) {
            half8 bf_h = *(const half8*)&Bh_s[wc * 64 + ni * 16 + c][g * 8];
            half8 bf_l = *(const half8*)&Bl_s[wc * 64 + ni * 16 + c][g * 8];
#pragma unroll
            for (int mi = 0; mi < 4; ++mi) {
                acc[mi][ni] = __builtin_amdgcn_mfma_f32_16x16x32_f16(af_h[mi], bf_h, acc[mi][ni], 0, 0, 0);
                acc[mi][ni] = __builtin_amdgcn_mfma_f32_16x16x32_f16(af_h[mi], bf_l, acc[mi][ni], 0, 0, 0);
                acc[mi][ni] = __builtin_amdgcn_mfma_f32_16x16x32_f16(af_l[mi], bf_h, acc[mi][ni], 0, 0, 0);
            }
        }
    }

#pragma unroll
    for (int ni = 0; ni < 4; ++ni) {
        int col = n0 + wc * 64 + ni * 16 + c;
        float bv = bias ? bias[col] : 0.f;
#pragma unroll
        for (int mi = 0; mi < 4; ++mi) {
#pragma unroll
            for (int r = 0; r < 4; ++r) {
                int row = m0 + wr * 64 + mi * 16 + 4 * g + r;
                if (row < M) Cout[(size_t)row * Nout + col] = acc[mi][ni][r] + bv;
            }
        }
    }
}

// ======================= MFMA attention v2 (pre-split planes, swizzled V^T) =======================
__global__ __launch_bounds__(256, 3) void attn_mfma(const _Float16* __restrict__ qkvh,
                                                    const _Float16* __restrict__ qkvl,
                                                    const _Float16* __restrict__ bias_pad,
                                                    _Float16* __restrict__ attnh,
                                                    _Float16* __restrict__ attnl) {
    __shared__ __attribute__((aligned(16))) _Float16 Kh[64][72];
    __shared__ __attribute__((aligned(16))) _Float16 Kl[64][72];
    __shared__ __attribute__((aligned(16))) _Float16 VhS[64 * 64];  // V^T [d][key], XOR-swizzled
    __shared__ __attribute__((aligned(16))) _Float16 VlS[64 * 64];
    __shared__ __attribute__((aligned(16))) _Float16 Pb[4][32][72];

    int bh = blockIdx.y;
    int h = bh >> 4, b = bh & 15;   // consecutive blocks share head h -> bias L2 locality
    int tid = threadIdx.x;
    int wave = tid >> 6, lane = tid & 63;
    int g = lane >> 4, c = lane & 15;
    int row0 = blockIdx.x * 128 + wave * 32;
    char* vhb = (char*)VhS;
    char* vlb = (char*)VlS;

    // ---- Q fragments: direct pre-scaled half8 loads ----
    half8 qh[2][2], ql[2][2];
#pragma unroll
    for (int rt = 0; rt < 2; ++rt) {
        int grow = row0 + rt * 16 + c;
#pragma unroll
        for (int kb = 0; kb < 2; ++kb) {
            half8 zh = {}, zl = {};
            if (grow < N_) {
                size_t off = (size_t)(b * N_ + grow) * QKV_N + h * HD_ + kb * 32 + g * 8;
                zh = *(const half8*)(qkvh + off);
                zl = *(const half8*)(qkvl + off);
            }
            qh[rt][kb] = zh; ql[rt][kb] = zl;
        }
    }

    floatx4 o[2][4];
    float mrun[2][4], lrun[2][4];
#pragma unroll
    for (int rt = 0; rt < 2; ++rt) {
#pragma unroll
        for (int t = 0; t < 4; ++t) { o[rt][t][0] = 0.f; o[rt][t][1] = 0.f; o[rt][t][2] = 0.f; o[rt][t][3] = 0.f; }
#pragma unroll
        for (int r = 0; r < 4; ++r) { mrun[rt][r] = -1e30f; lrun[rt][r] = 0.f; }
    }

    for (int j0 = 0; j0 < N_; j0 += 64) {
        __syncthreads();
        // ---- stage K (b128) + V^T (swizzled scalar) from pre-split planes ----
#pragma unroll
        for (int pass = 0; pass < 2; ++pass) {
            int idx = pass * 256 + tid;
            int key = idx >> 3;
            int d0 = (idx & 7) << 3;
            int j = j0 + key;
            half8 khv = {}, klv = {}, vhv = {}, vlv = {};
            if (j < N_) {
                size_t gb = (size_t)(b * N_ + j) * QKV_N + h * HD_ + d0;
                khv = *(const half8*)(qkvh + gb + 768);
                klv = *(const half8*)(qkvl + gb + 768);
                vhv = *(const half8*)(qkvh + gb + 1536);
                vlv = *(const half8*)(qkvl + gb + 1536);
            }
            *(half8*)&Kh[key][d0] = khv;
            *(half8*)&Kl[key][d0] = klv;
#pragma unroll
            for (int i = 0; i < 8; ++i) {
                int d = d0 + i;
                int cb = (key * 2) ^ (((d & 7) ^ ((d >> 3) & 7)) << 4);
                *(_Float16*)(vhb + d * 128 + cb) = vhv[i];
                *(_Float16*)(vlb + d * 128 + cb) = vlv[i];
            }
        }
        __syncthreads();

        // ---- bias: clamp-free coalesced loads from padded table ----
        float bv[2][4][4];
#pragma unroll
        for (int rt = 0; rt < 2; ++rt)
#pragma unroll
            for (int t = 0; t < 4; ++t)
#pragma unroll
                for (int r = 0; r < 4; ++r)
                    bv[rt][t][r] = (float)bias_pad[((size_t)h * BIAS_DIM + row0 + rt * 16 + 4 * g + r) * BIAS_DIM
                                                   + j0 + t * 16 + c];

        // ---- S = Q K^T (3-term split) ----
        floatx4 s[2][4];
#pragma unroll
        for (int rt = 0; rt < 2; ++rt)
#pragma unroll
            for (int t = 0; t < 4; ++t) { s[rt][t][0] = 0.f; s[rt][t][1] = 0.f; s[rt][t][2] = 0.f; s[rt][t][3] = 0.f; }
#pragma unroll
        for (int t = 0; t < 4; ++t) {
#pragma unroll
            for (int kb = 0; kb < 2; ++kb) {
                half8 kh8 = *(const half8*)&Kh[t * 16 + c][kb * 32 + g * 8];
                half8 kl8 = *(const half8*)&Kl[t * 16 + c][kb * 32 + g * 8];
#pragma unroll
                for (int rt = 0; rt < 2; ++rt) {
                    s[rt][t] = __builtin_amdgcn_mfma_f32_16x16x32_f16(qh[rt][kb], kh8, s[rt][t], 0, 0, 0);
                    s[rt][t] = __builtin_amdgcn_mfma_f32_16x16x32_f16(qh[rt][kb], kl8, s[rt][t], 0, 0, 0);
                    s[rt][t] = __builtin_amdgcn_mfma_f32_16x16x32_f16(ql[rt][kb], kh8, s[rt][t], 0, 0, 0);
                }
            }
        }

        // ---- online softmax ----
#pragma unroll
        for (int rt = 0; rt < 2; ++rt) {
#pragma unroll
            for (int t = 0; t < 4; ++t)
#pragma unroll
                for (int r = 0; r < 4; ++r) s[rt][t][r] += bv[rt][t][r];
            float pm[4], mnew[4], corr[4], rs[4];
#pragma unroll
            for (int r = 0; r < 4; ++r)
                pm[r] = fmaxf(fmaxf(s[rt][0][r], s[rt][1][r]), fmaxf(s[rt][2][r], s[rt][3][r]));
#pragma unroll
            for (int r = 0; r < 4; ++r) {
                pm[r] = fmaxf(pm[r], __shfl_xor(pm[r], 1));
                pm[r] = fmaxf(pm[r], __shfl_xor(pm[r], 2));
                pm[r] = fmaxf(pm[r], __shfl_xor(pm[r], 4));
                pm[r] = fmaxf(pm[r], __shfl_xor(pm[r], 8));
                mnew[r] = fmaxf(mrun[rt][r], pm[r]);
                corr[r] = __expf(mrun[rt][r] - mnew[r]);
                rs[r] = 0.f;
            }
#pragma unroll
            for (int t = 0; t < 4; ++t)
#pragma unroll
                for (int r = 0; r < 4; ++r) {
                    float p = __expf(s[rt][t][r] - mnew[r]);
                    s[rt][t][r] = p;
                    rs[r] += p;
                }
#pragma unroll
            for (int r = 0; r < 4; ++r) {
                rs[r] += __shfl_xor(rs[r], 1);
                rs[r] += __shfl_xor(rs[r], 2);
                rs[r] += __shfl_xor(rs[r], 4);
                rs[r] += __shfl_xor(rs[r], 8);
                lrun[rt][r] = lrun[rt][r] * corr[r] + rs[r];
                mrun[rt][r] = mnew[r];
            }
#pragma unroll
            for (int t = 0; t < 4; ++t)
#pragma unroll
                for (int r = 0; r < 4; ++r) o[rt][t][r] *= corr[r];
#pragma unroll
            for (int t = 0; t < 4; ++t)
#pragma unroll
                for (int r = 0; r < 4; ++r)
                    Pb[wave][rt * 16 + 4 * g + r][t * 16 + c] = (_Float16)s[rt][t][r];
        }

        // ---- O += P @ V (swizzled V^T reads) ----
#pragma unroll
        for (int kb = 0; kb < 2; ++kb) {
            half8 pa[2];
#pragma unroll
            for (int rt = 0; rt < 2; ++rt)
                pa[rt] = *(const half8*)&Pb[wave][rt * 16 + c][kb * 32 + g * 8];
#pragma unroll
            for (int t = 0; t < 4; ++t) {
                int row = t * 16 + c;
                int cb = (kb * 64 + g * 16) ^ (((row & 7) ^ ((row >> 3) & 7)) << 4);
                half8 vh8 = *(const half8*)(vhb + row * 128 + cb);
                half8 vl8 = *(const half8*)(vlb + row * 128 + cb);
#pragma unroll
                for (int rt = 0; rt < 2; ++rt) {
                    o[rt][t] = __builtin_amdgcn_mfma_f32_16x16x32_f16(pa[rt], vh8, o[rt][t], 0, 0, 0);
                    o[rt][t] = __builtin_amdgcn_mfma_f32_16x16x32_f16(pa[rt], vl8, o[rt][t], 0, 0, 0);
                }
            }
        }
    }

    // ---- epilogue: normalize, write hi/lo planes ----
#pragma unroll
    for (int rt = 0; rt < 2; ++rt)
#pragma unroll
        for (int t = 0; t < 4; ++t)
#pragma unroll
            for (int r = 0; r < 4; ++r) {
                int row = row0 + rt * 16 + 4 * g + r;
                if (row < N_) {
                    float val = o[rt][t][r] / lrun[rt][r];
                    size_t idx = (size_t)(b * N_ + row) * C_ + h * HD_ + t * 16 + c;
                    _Float16 hi = (_Float16)val;
                    attnh[idx] = hi;
                    attnl[idx] = (_Float16)(val - (float)hi);
                }
            }
}

// ======================= cls: per-(b,h) softmax row 0 (fp32, stride 1536) =======================
__global__ __launch_bounds__(256) void cls_head_kernel(const float* __restrict__ qkv32,
                                                       const float* __restrict__ bias_table,
                                                       const int* __restrict__ rel_index,
                                                       float* __restrict__ cls_part) {
    int b = blockIdx.x, h = blockIdx.y;
    __shared__ float q0[64];
    __shared__ float s[N_];
    __shared__ float red[256];
    int tid = threadIdx.x;
    if (tid < 64) q0[tid] = qkv32[(size_t)(b * N_) * QK32_N + h * HD_ + tid] * 0.125f;
    __syncthreads();
    for (int j = tid; j < N_; j += 256) {
        const float* kr = qkv32 + (size_t)(b * N_ + j) * QK32_N + 768 + h * HD_;
        float d = 0.f;
        for (int kk = 0; kk < 64; ++kk) d += q0[kk] * kr[kk];
        s[j] = d + bias_table[rel_index[j] * H_ + h];
    }
    __syncthreads();
    float mx = -1e30f;
    for (int j = tid; j < N_; j += 256) mx = fmaxf(mx, s[j]);
    red[tid] = mx;
    __syncthreads();
    for (int st = 128; st > 0; st >>= 1) {
        if (tid < st) red[tid] = fmaxf(red[tid], red[tid + st]);
        __syncthreads();
    }
    float m = red[0];
    __syncthreads();
    float ssum = 0.f;
    for (int j = tid; j < N_; j += 256) ssum += expf(s[j] - m);
    red[tid] = ssum;
    __syncthreads();
    for (int st = 128; st > 0; st >>= 1) {
        if (tid < st) red[tid] += red[tid + st];
        __syncthreads();
    }
    float tot = red[0];
    __syncthreads();
    float* dst = cls_part + (size_t)(b * H_ + h) * NIMG;
    for (int j = tid; j < NIMG; j += 256) dst[j] = expf(s[j + 1] - m) / tot;
}

__global__ __launch_bounds__(576) void cls_reduce_kernel(const float* __restrict__ cls_part,
                                                         float* __restrict__ cls) {
    int b = blockIdx.x;
    int j = threadIdx.x;
    float a = 0.f;
    for (int h = 0; h < H_; ++h) a += cls_part[(size_t)(b * H_ + h) * NIMG + j];
    cls[b * NIMG + j] = a * (1.0f / 12.0f);
}

// ======================= threefry2x32 (JAX) =======================
__device__ __forceinline__ void tf2x32(unsigned k0, unsigned k1, unsigned x0, unsigned x1,
                                       unsigned& o0, unsigned& o1) {
    unsigned ks2 = k0 ^ k1 ^ 0x1BD11BDAu;
    x0 += k0; x1 += k1;
#define ROTL_(v, d) (((v) << (d)) | ((v) >> (32 - (d))))
#define RND_(d) { x0 += x1; x1 = ROTL_(x1, d); x1 ^= x0; }
    RND_(13) RND_(15) RND_(26) RND_(6)
    x0 += k1; x1 += ks2 + 1u;
    RND_(17) RND_(29) RND_(16) RND_(24)
    x0 += ks2; x1 += k0 + 2u;
    RND_(13) RND_(15) RND_(26) RND_(6)
    x0 += k0; x1 += k1 + 3u;
    RND_(17) RND_(29) RND_(16) RND_(24)
    x0 += k1; x1 += ks2 + 4u;
    RND_(13) RND_(15) RND_(26) RND_(6)
    x0 += ks2; x1 += k0 + 5u;
    o0 = x0; o1 = x1;
#undef RND_
#undef ROTL_
}

// ======================= selection + img_idx =======================
__global__ __launch_bounds__(256) void select_kernel(const float* __restrict__ cls,
                                                     const float* __restrict__ token_w,
                                                     int* __restrict__ meta,
                                                     int* __restrict__ keep_idx,
                                                     int* __restrict__ img_idx) {
    __shared__ float red[256];
    __shared__ int ired[256];
    __shared__ int counts[16];
    __shared__ float c0[NIMG];
    __shared__ int keep_sh, nimg_sh;
    int tid = threadIdx.x;

    for (int b = 0; b < 16; ++b) {
        float sm = 0.f;
        for (int j = tid; j < NIMG; j += 256) sm += cls[b * NIMG + j];
        red[tid] = sm;
        __syncthreads();
        for (int st = 128; st > 0; st >>= 1) {
            if (tid < st) red[tid] += red[tid + st];
            __syncthreads();
        }
        float avg = red[0] * (1.0f / 576.0f);
        __syncthreads();
        int cnt = 0;
        for (int j = tid; j < NIMG; j += 256) cnt += (cls[b * NIMG + j] >= avg) ? 1 : 0;
        ired[tid] = cnt;
        __syncthreads();
        for (int st = 128; st > 0; st >>= 1) {
            if (tid < st) ired[tid] += ired[tid + st];
            __syncthreads();
        }
        if (tid == 0) counts[b] = ired[0];
        __syncthreads();
    }

    if (tid == 0) {
        int csum = 0, cmax = 0;
        for (int b2 = 0; b2 < 16; ++b2) {
            csum += counts[b2];
            if (counts[b2] > cmax) cmax = counts[b2];
        }
        double T = (double)csum / 16.0;
        double sig = 1.0 / (1.0 + exp(-(((double)cmax) - T) / 16.0));
        double kd = 576.0 * (0.6 + 0.4 * sig);
        int keep = (int)llrint(kd);
        int remaining = NIMG - keep;
        float w0 = token_w[0], w1 = token_w[1];
        float wm = fmaxf(w0, w1);
        float e0 = expf(w0 - wm), e1 = expf(w1 - wm);
        float wsm = e0 / (e0 + e1);
        int ntext = (int)((double)wsm * (double)remaining);
        int nimg = remaining - ntext;
        meta[0] = keep; meta[1] = ntext; meta[2] = nimg;
        keep_sh = keep; nimg_sh = nimg;
    }
    __syncthreads();

    for (int j = tid; j < NIMG; j += 256) c0[j] = cls[j];
    __syncthreads();
    int keep = keep_sh;
    for (int j = tid; j < NIMG; j += 256) {
        float v = c0[j];
        int rank = 0;
        for (int j2 = 0; j2 < NIMG; ++j2) {
            float v2 = c0[j2];
            rank += ((v2 > v) || (v2 == v && j2 < j)) ? 1 : 0;
        }
        if (rank < keep) keep_idx[rank] = j;
    }

    unsigned ki0, ki1, k1a, k1b, k2a, k2b;
    tf2x32(0u, 1u, 0u, 1u, ki0, ki1);
    tf2x32(ki0, ki1, 0u, 0u, k1a, k1b);
    tf2x32(ki0, ki1, 0u, 1u, k2a, k2b);
    int nimg = nimg_sh;
    int S = 16 * nimg;
    const unsigned span = 575u;
    const unsigned mult = ((65536u % span) * (65536u % span)) % span;
    for (int i = tid; i < S; i += 256) {
        unsigned h0, h1, l0, l1;
        tf2x32(k1a, k1b, 0u, (unsigned)i, h0, h1);
        tf2x32(k2a, k2b, 0u, (unsigned)i, l0, l1);
        unsigned hb = h0 ^ h1;
        unsigned lb = l0 ^ l1;
        unsigned off = ((hb % span) * mult + (lb % span)) % span;
        img_idx[i] = (int)off;
    }
}

// ======================= assemble output =======================
__global__ __launch_bounds__(192) void assemble_kernel(const float* __restrict__ xout,
                                                       const float* __restrict__ x,
                                                       const int* __restrict__ meta,
                                                       const int* __restrict__ keep_idx,
                                                       const int* __restrict__ img_idx,
                                                       float* __restrict__ out) {
    int gb = blockIdx.x;
    int token = gb % N_;
    int b = gb / N_;
    int keep = meta[0], ntext = meta[1], nimg = meta[2];
    const float* src;
    if (token == 0) {
        src = xout + (size_t)(b * N_) * C_;
    } else if (token <= keep) {
        src = xout + (size_t)(b * N_ + 1 + keep_idx[token - 1]) * C_;
    } else if (token <= keep + ntext) {
        src = x + (size_t)(b * N_ + 1) * C_;
    } else {
        int t = token - 1 - keep - ntext;
        src = x + (size_t)(b * N_ + 2 + img_idx[b * nimg + t]) * C_;
    }
    float4* d = (float4*)(out + (size_t)(b * N_ + token) * C_);
    d[threadIdx.x] = ((const float4*)src)[threadIdx.x];
}

// ======================= launch =======================
extern "C" void kernel_launch(void* const* d_in, const int* in_sizes, int n_in,
                              void* d_out, int out_size, void* d_ws, size_t ws_size,
                              hipStream_t stream) {
    const float* x          = (const float*)d_in[0];
    const float* qkv_w      = (const float*)d_in[1];
    const float* proj_w     = (const float*)d_in[2];
    const float* proj_b     = (const float*)d_in[3];
    const float* bias_table = (const float*)d_in[4];
    const float* token_w    = (const float*)d_in[5];
    const int*   rel_index  = (const int*)d_in[6];
    float* out = (float*)d_out;
    float* ws  = (float*)d_ws;

    float*     qkv32    = ws + OFF_QKV32;                       // alive: gemm..select
    _Float16*  attnh    = (_Float16*)(ws + OFF_ATTNH);          // aliases qkv32 (dead by attn)
    _Float16*  attnl    = (_Float16*)(ws + OFF_ATTNL);
    float*     xout     = ws + OFF_XOUT;
    _Float16*  qkvh     = (_Float16*)(ws + OFF_QKVH);
    _Float16*  qkvl     = (_Float16*)(ws + OFF_QKVL);
    float*     cls      = ws + OFF_CLS;
    float*     cls_part = ws + OFF_CLSPART;
    int*       meta     = (int*)(ws + OFF_META);
    int*       keep_idx = meta + 8;
    int*       img_idx  = keep_idx + 576;
    _Float16*  wqkvh    = (_Float16*)(ws + OFF_WQKVH);
    _Float16*  wqkvl    = (_Float16*)(ws + OFF_WQKVL);
    _Float16*  wprojh   = (_Float16*)(ws + OFF_WPROJH);
    _Float16*  wprojl   = (_Float16*)(ws + OFF_WPROJL);
    _Float16*  bias_pad = (_Float16*)(ws + OFF_BIASPAD);

    // 0) weight splits + padded bias expansion
    split_kernel<<<dim3(QKV_N * C_ / 1024), 256, 0, stream>>>(qkv_w, wqkvh, wqkvl, QKV_N * C_);
    split_kernel<<<dim3(C_ * C_ / 1024), 256, 0, stream>>>(proj_w, wprojh, wprojl, C_ * C_);
    bias_expand<<<dim3(BIAS_DIM, H_), 256, 0, stream>>>(bias_table, rel_index, bias_pad);
    // 1) qkv GEMM: fp32 Q|K (cls) + pre-scaled hi/lo planes (attn)
    hgemm_qkv<<<dim3(QKV_N / 128, (M_ + 127) / 128), 256, 0, stream>>>(
        x, wqkvh, wqkvl, qkv32, qkvh, qkvl);
    // 2) cls_attn (fp32, deterministic — selection path untouched)
    cls_head_kernel<<<dim3(B_, H_), 256, 0, stream>>>(qkv32, bias_table, rel_index, cls_part);
    cls_reduce_kernel<<<dim3(B_), 576, 0, stream>>>(cls_part, cls);
    // 3) selection scalars + top-k + threefry img_idx
    select_kernel<<<dim3(1), 256, 0, stream>>>(cls, token_w, meta, keep_idx, img_idx);
    // 4) MFMA attention v2 (qkv32 now dead; attnh/attnl alias its region)
    attn_mfma<<<dim3((N_ + 127) / 128, B_ * H_), 256, 0, stream>>>(
        qkvh, qkvl, bias_pad, attnh, attnl);
    // 5) proj GEMM
    hgemm_nt_split<<<dim3(C_ / 128, (M_ + 127) / 128), 256, 0, stream>>>(
        attnh, attnl, wprojh, wprojl, proj_b, xout, M_, C_);
    // 6) gather/concat final tokens
    assemble_kernel<<<dim3(B_ * N_), 192, 0, stream>>>(
        xout, x, meta, keep_idx, img_idx, out);
}